// Round 7
// baseline (323.475 us; speedup 1.0000x reference)
//
#include <hip/hip_runtime.h>
#include <hip/hip_bf16.h>

#define K_IN   1044
#define N_FEAT 128
#define KPAD   1056   // 33 * 32
#define LDA    40     // LDS row pitch in bf16 elems (32 + 8 pad = 80 B)
#define NSTEP  (KPAD / 32)   // 33

#define NB     512    // coarse buckets for counting sort
#define BWMAX  256    // max nodes per bucket (runtime bw = ceil(N/NB) = 137)
#define EPB    8192   // edges per block in hist/stage

typedef __attribute__((ext_vector_type(8))) short short8;
typedef __attribute__((ext_vector_type(4))) float f32x4;

__device__ __forceinline__ ushort f2bf(float f) {
  unsigned x = __float_as_uint(f);
  x += 0x7fffu + ((x >> 16) & 1u);   // round-to-nearest-even
  return (ushort)(x >> 16);
}
// packed pair conversion: compiler lowers to v_cvt_pk_bf16_f32
__device__ __forceinline__ uint pkbf(float lo, float hi) {
  __hip_bfloat162 h = __float22bfloat162_rn(make_float2(lo, hi));
  return *reinterpret_cast<uint*>(&h);
}
__device__ __forceinline__ float bflo(uint v) { return __uint_as_float(v << 16); }
__device__ __forceinline__ float bfhi(uint v) { return __uint_as_float(v & 0xFFFF0000u); }

// ================= CSR build: bucketed counting sort =================

__global__ __launch_bounds__(256) void csr_hist_kernel(const int* __restrict__ dst,
                                                       int* __restrict__ bt, int E, int bw) {
  __shared__ int h[NB];
  const int t = threadIdx.x;
  for (int i = t; i < NB; i += 256) h[i] = 0;
  __syncthreads();
  const int e0 = blockIdx.x * EPB;
  const int e1 = min(e0 + EPB, E);
  for (int e = e0 + t; e < e1; e += 256) atomicAdd(&h[dst[e] / bw], 1);
  __syncthreads();
  for (int i = t; i < NB; i += 256)
    if (h[i]) atomicAdd(&bt[i], h[i]);
}

__global__ __launch_bounds__(256) void csr_bucket_scan_kernel(const int* __restrict__ bt,
                                                              int* __restrict__ bucket_base,
                                                              int* __restrict__ bucket_cursor) {
  __shared__ int sc[256];
  const int t = threadIdx.x;
  int v0 = bt[2 * t], v1 = bt[2 * t + 1];
  int s = v0 + v1;
  sc[t] = s;
  __syncthreads();
  for (int off = 1; off < 256; off <<= 1) {
    int x = (t >= off) ? sc[t - off] : 0;
    __syncthreads();
    sc[t] += x;
    __syncthreads();
  }
  int excl = sc[t] - s;
  bucket_base[2 * t]     = excl;
  bucket_base[2 * t + 1] = excl + v0;
  bucket_cursor[2 * t]     = excl;
  bucket_cursor[2 * t + 1] = excl + v0;
  if (t == 255) bucket_base[NB] = sc[255];
}

__global__ __launch_bounds__(256) void csr_stage_kernel(const int* __restrict__ src,
                                                        const int* __restrict__ dst,
                                                        int* __restrict__ bucket_cursor,
                                                        uint2* __restrict__ staging, int E, int bw) {
  __shared__ int h[NB];
  __shared__ int cur[NB];
  const int t = threadIdx.x;
  for (int i = t; i < NB; i += 256) h[i] = 0;
  __syncthreads();
  const int e0 = blockIdx.x * EPB;
  const int e1 = min(e0 + EPB, E);
  for (int e = e0 + t; e < e1; e += 256) atomicAdd(&h[dst[e] / bw], 1);
  __syncthreads();
  for (int i = t; i < NB; i += 256)
    cur[i] = h[i] ? atomicAdd(&bucket_cursor[i], h[i]) : 0;
  __syncthreads();
  for (int e = e0 + t; e < e1; e += 256) {
    int d = dst[e];
    int p = atomicAdd(&cur[d / bw], 1);
    staging[p] = make_uint2((uint)src[e], (uint)d);
  }
}

// one block per bucket: node histogram + scan + scatter -> row_ptr, sorted_src, dinv
__global__ __launch_bounds__(256) void csr_final_kernel(const uint2* __restrict__ staging,
                                                        const int* __restrict__ bucket_base,
                                                        int* __restrict__ row_ptr,
                                                        int* __restrict__ sorted_src,
                                                        float* __restrict__ dinv,
                                                        int N, int bw, int E) {
  __shared__ int hist[BWMAX];
  __shared__ int sc[256];
  const int b = blockIdx.x;
  const int t = threadIdx.x;
  if (b == 0 && t == 0) row_ptr[N] = E;
  const int node0 = b * bw;
  const int nn = min(bw, N - node0);
  if (nn <= 0) return;
  const int base = bucket_base[b];
  const int cnt  = bucket_base[b + 1] - base;

  for (int i = t; i < BWMAX; i += 256) hist[i] = 0;
  __syncthreads();
  for (int i = t; i < cnt; i += 256) {
    uint2 p = staging[base + i];
    atomicAdd(&hist[(int)p.y - node0], 1);
  }
  __syncthreads();
  int v = (t < nn) ? hist[t] : 0;
  if (t < nn) dinv[node0 + t] = rsqrtf((float)(v + 1));   // +1 self-loop
  sc[t] = v;
  __syncthreads();
  for (int off = 1; off < 256; off <<= 1) {
    int x = (t >= off) ? sc[t - off] : 0;
    __syncthreads();
    sc[t] += x;
    __syncthreads();
  }
  int excl = sc[t] - v;
  if (t < nn) row_ptr[node0 + t] = base + excl;
  if (t < nn) hist[t] = excl;   // reuse as cursors
  __syncthreads();
  for (int i = t; i < cnt; i += 256) {
    uint2 p = staging[base + i];
    int c = atomicAdd(&hist[(int)p.y - node0], 1);
    sorted_src[base + c] = (int)p.x;
  }
}

// ---------------- W1 -> bf16 transposed [128][KPAD] ----------------

__global__ void convert_w1_kernel(const float* __restrict__ W1, ushort* __restrict__ W1T) {
  int idx = blockIdx.x * blockDim.x + threadIdx.x;
  if (idx >= N_FEAT * KPAD) return;
  int c = idx / KPAD, k = idx - c * KPAD;
  W1T[idx] = (k < K_IN) ? f2bf(W1[(size_t)k * N_FEAT + c]) : (ushort)0;
}

// ---------------- layer 1 GEMM (MFMA bf16): g1 = dinv * (X @ W1), stored bf16 ----------------
// BM=64, BN=128, BK=32; 256 threads = 4 waves (2x2), wave tile 32x64 = 2x4 frags.
// Depth-2 register pipeline: step s issues loads for s+2 into the set freed at
// s-1; store_step consumes a set loaded TWO iters ago (~full HBM latency hidden).
// Raw s_barrier (no vmcnt drain) + explicit lgkmcnt(0) fence for LDS writes.

__global__ __launch_bounds__(256) void gemm1_mfma_kernel(const float* __restrict__ X,
                                                         const ushort* __restrict__ W1T,
                                                         const float* __restrict__ dinv,
                                                         ushort* __restrict__ G1, int M) {
  __shared__ ushort Asb[2][64 * LDA];    // 10 KB
  __shared__ ushort Bsb[2][128 * LDA];   // 20 KB

  const int t = threadIdx.x;
  const int row0 = blockIdx.x * 64;

  const int ar = t >> 2;            // A row 0..63 (4 threads/row)
  const int ak = (t & 3) * 8;       // k offset 0,8,16,24
  const int br = t >> 1;            // B row (output col) 0..127
  const int bk = (t & 1) * 16;      // k offset 0,16

  const bool arv = (row0 + ar) < M;
  const float*  aptr = X + (size_t)(row0 + ar) * K_IN;
  const ushort* bptr = W1T + (size_t)br * KPAD;

  const int l = t & 63;
  const int wid = t >> 6;
  const int wm = wid >> 1, wn = wid & 1;
  const int lr = l & 15;
  const int lko = (l >> 4) * 8;

  f32x4 acc[2][4] = {};

  // two named register sets (static indexing only)
  float4 pa0A, pa1A; uint4 pb0A, pb1A;
  float4 pa0B, pa1B; uint4 pb0B, pb1B;

#define LOADSET(PA0, PA1, PB0, PB1, S)                                  \
  do {                                                                  \
    const int kk_ = (S) * 32;                                           \
    const int gk_ = kk_ + ak;                                           \
    if (arv && gk_ + 8 <= K_IN) {                                       \
      const float4* p_ = (const float4*)(aptr + gk_);                   \
      PA0 = p_[0]; PA1 = p_[1];                                         \
    } else {                                                            \
      float tmp_[8];                                                    \
      _Pragma("unroll")                                                 \
      for (int j_ = 0; j_ < 8; j_++)                                    \
        tmp_[j_] = (arv && gk_ + j_ < K_IN) ? aptr[gk_ + j_] : 0.f;     \
      PA0 = make_float4(tmp_[0], tmp_[1], tmp_[2], tmp_[3]);            \
      PA1 = make_float4(tmp_[4], tmp_[5], tmp_[6], tmp_[7]);            \
    }                                                                   \
    const uint4* q_ = (const uint4*)(bptr + kk_ + bk);                  \
    PB0 = q_[0]; PB1 = q_[1];                                           \
  } while (0)

#define STORESET(BUF, PA0, PA1, PB0, PB1)                               \
  do {                                                                  \
    uint w0_ = pkbf(PA0.x, PA0.y), w1_ = pkbf(PA0.z, PA0.w);            \
    uint w2_ = pkbf(PA1.x, PA1.y), w3_ = pkbf(PA1.z, PA1.w);            \
    *(uint4*)&Asb[BUF][ar * LDA + ak] = make_uint4(w0_, w1_, w2_, w3_); \
    *(uint4*)&Bsb[BUF][br * LDA + bk]     = PB0;                        \
    *(uint4*)&Bsb[BUF][br * LDA + bk + 8] = PB1;                        \
  } while (0)

#define FENCE_BARRIER()                                                 \
  do {                                                                  \
    asm volatile("s_waitcnt lgkmcnt(0)" ::: "memory");                  \
    __builtin_amdgcn_sched_barrier(0);                                  \
    __builtin_amdgcn_s_barrier();                                       \
  } while (0)

  // prologue: step0 -> setA -> LDS[0]; step1 -> setB (in flight)
  LOADSET(pa0A, pa1A, pb0A, pb1A, 0);
  LOADSET(pa0B, pa1B, pb0B, pb1B, 1);
  STORESET(0, pa0A, pa1A, pb0A, pb1A);
  FENCE_BARRIER();

  for (int s = 0; s < NSTEP; s++) {
    const int cur = s & 1;
    // issue loads for step s+2 into the set freed at iter s-1
    if (s + 2 < NSTEP) {
      if (cur == 0) LOADSET(pa0A, pa1A, pb0A, pb1A, s + 2);
      else          LOADSET(pa0B, pa1B, pb0B, pb1B, s + 2);
    }

    short8 af[2], bfr[4];
    #pragma unroll
    for (int m = 0; m < 2; m++)
      af[m] = *(const short8*)&Asb[cur][(wm * 32 + m * 16 + lr) * LDA + lko];
    #pragma unroll
    for (int n = 0; n < 4; n++)
      bfr[n] = *(const short8*)&Bsb[cur][(wn * 64 + n * 16 + lr) * LDA + lko];

    #pragma unroll
    for (int m = 0; m < 2; m++)
      #pragma unroll
      for (int n = 0; n < 4; n++)
        acc[m][n] = __builtin_amdgcn_mfma_f32_16x16x32_bf16(af[m], bfr[n], acc[m][n], 0, 0, 0);

    // write step s+1 (loaded two iters ago) into the other buffer
    if (s + 1 < NSTEP) {
      if (cur == 0) STORESET(1, pa0B, pa1B, pb0B, pb1B);
      else          STORESET(0, pa0A, pa1A, pb0A, pb1A);
    }
    FENCE_BARRIER();
  }
#undef LOADSET
#undef STORESET
#undef FENCE_BARRIER

  const int rbase = row0 + wm * 32 + (l >> 4) * 4;
  const int cbase = wn * 64 + lr;
  #pragma unroll
  for (int m = 0; m < 2; m++) {
    #pragma unroll
    for (int r = 0; r < 4; r++) {
      int row = rbase + m * 16 + r;
      if (row < M) {
        float dv = dinv[row];
        #pragma unroll
        for (int n = 0; n < 4; n++)
          G1[(size_t)row * N_FEAT + cbase + n * 16] = f2bf(dv * acc[m][n][r]);
      }
    }
  }
}

// ---------------- layer 1 aggregation ----------------

__global__ __launch_bounds__(256) void agg1_kernel(const ushort* __restrict__ G1,
                                                   const int* __restrict__ row_ptr,
                                                   const int* __restrict__ sorted_src,
                                                   const float* __restrict__ dinv,
                                                   const float* __restrict__ b1,
                                                   float* __restrict__ x1, int N) {
  const int w = (blockIdx.x * blockDim.x + threadIdx.x) >> 6;
  const int lane = threadIdx.x & 63;
  if (w >= N) return;
  const int beg = row_ptr[w], end = row_ptr[w + 1];
  const uint* g1u = (const uint*)G1;
  const int co = lane;

  uint vs = g1u[((size_t)w << 6) + co];
  float a0 = bflo(vs), a1 = bfhi(vs);

  int e = beg;
  for (; e + 8 <= end; e += 8) {
    int s[8];
    #pragma unroll
    for (int i = 0; i < 8; i++) s[i] = sorted_src[e + i];
    #pragma unroll
    for (int i = 0; i < 8; i++) {
      uint v = g1u[((size_t)s[i] << 6) + co];
      a0 += bflo(v); a1 += bfhi(v);
    }
  }
  for (; e < end; e++) {
    uint v = g1u[((size_t)sorted_src[e] << 6) + co];
    a0 += bflo(v); a1 += bfhi(v);
  }

  const float di = dinv[w];
  float r0 = fmaxf(fmaf(di, a0, b1[2 * co + 0]), 0.f);
  float r1 = fmaxf(fmaf(di, a1, b1[2 * co + 1]), 0.f);
  *(float2*)&x1[((size_t)w << 7) + 2 * co] = make_float2(r0, r1);
}

// ---------------- layer 2 GEMM ----------------

__global__ __launch_bounds__(256) void gemm2_kernel(const float* __restrict__ X,
                                                    const float* __restrict__ W,  // [128][3]
                                                    const float* __restrict__ dinv,
                                                    float* __restrict__ H, int M) {
  int t = blockIdx.x * blockDim.x + threadIdx.x;
  int wid = t >> 6, lane = t & 63;
  if (wid >= M) return;
  float2 xv = ((const float2*)(X + (size_t)wid * N_FEAT))[lane];
  int r0 = 2 * lane, r1 = r0 + 1;
  float s0 = xv.x * W[r0 * 3 + 0] + xv.y * W[r1 * 3 + 0];
  float s1 = xv.x * W[r0 * 3 + 1] + xv.y * W[r1 * 3 + 1];
  float s2 = xv.x * W[r0 * 3 + 2] + xv.y * W[r1 * 3 + 2];
  #pragma unroll
  for (int off = 32; off > 0; off >>= 1) {
    s0 += __shfl_down(s0, off);
    s1 += __shfl_down(s1, off);
    s2 += __shfl_down(s2, off);
  }
  if (lane == 0) {
    float dv = dinv[wid];
    H[wid * 3 + 0] = dv * s0;
    H[wid * 3 + 1] = dv * s1;
    H[wid * 3 + 2] = dv * s2;
  }
}

// ---------------- layer 2 aggregation ----------------

__global__ __launch_bounds__(256) void agg2_kernel(const float* __restrict__ G2,
                                                   const int* __restrict__ row_ptr,
                                                   const int* __restrict__ sorted_src,
                                                   const float* __restrict__ dinv,
                                                   const float* __restrict__ b2,
                                                   float* __restrict__ out, int N) {
  int t = blockIdx.x * blockDim.x + threadIdx.x;
  int node = t >> 6, lane = t & 63;
  if (node >= N) return;
  int beg = row_ptr[node], end = row_ptr[node + 1];
  float a0 = 0.f, a1 = 0.f, a2 = 0.f;
  for (int e = beg + lane; e < end; e += 64) {
    int s = sorted_src[e];
    a0 += G2[s * 3 + 0];
    a1 += G2[s * 3 + 1];
    a2 += G2[s * 3 + 2];
  }
  #pragma unroll
  for (int off = 32; off > 0; off >>= 1) {
    a0 += __shfl_down(a0, off);
    a1 += __shfl_down(a1, off);
    a2 += __shfl_down(a2, off);
  }
  if (lane == 0) {
    float di = dinv[node];
    out[node * 3 + 0] = di * (a0 + G2[node * 3 + 0]) + b2[0];
    out[node * 3 + 1] = di * (a1 + G2[node * 3 + 1]) + b2[1];
    out[node * 3 + 2] = di * (a2 + G2[node * 3 + 2]) + b2[2];
  }
}

// ---------------- launch ----------------

extern "C" void kernel_launch(void* const* d_in, const int* in_sizes, int n_in,
                              void* d_out, int out_size, void* d_ws, size_t ws_size,
                              hipStream_t stream) {
  const float* features = (const float*)d_in[0];
  const int*   edges    = (const int*)d_in[1];
  const float* W1 = (const float*)d_in[4];
  const float* b1 = (const float*)d_in[5];
  const float* W2 = (const float*)d_in[6];
  const float* b2 = (const float*)d_in[7];
  float* out = (float*)d_out;

  const int N = in_sizes[0] / K_IN;   // 70000
  const int E = in_sizes[1] / 2;      // 2,000,000
  const int* src = edges;
  const int* dst = edges + E;
  const int bw = (N + NB - 1) / NB;   // 137

  char* ws = (char*)d_ws;
  size_t off = 0;
  auto alloc = [&](size_t bytes) {
    void* p = ws + off;
    off += (bytes + 255) & ~(size_t)255;
    return p;
  };
  int*    bt            = (int*)   alloc((size_t)NB * sizeof(int));
  int*    bucket_base   = (int*)   alloc((size_t)(NB + 1) * sizeof(int));
  int*    bucket_cursor = (int*)   alloc((size_t)NB * sizeof(int));
  int*    row_ptr       = (int*)   alloc((size_t)(N + 1) * sizeof(int));
  float*  dinv          = (float*) alloc((size_t)N * sizeof(float));
  uint2*  staging       = (uint2*) alloc((size_t)E * sizeof(uint2));
  int*    sorted_src    = (int*)   alloc((size_t)E * sizeof(int));
  ushort* G1            = (ushort*)alloc((size_t)N * N_FEAT * sizeof(ushort));
  float*  x1            = (float*) alloc((size_t)N * N_FEAT * sizeof(float));
  float*  G2            = (float*) alloc((size_t)N * 3 * sizeof(float));
  ushort* W1T           = (ushort*)alloc((size_t)N_FEAT * KPAD * sizeof(ushort));
  (void)ws_size;

  const int eblocks = (E + EPB - 1) / EPB;

  hipMemsetAsync(bt, 0, (size_t)NB * sizeof(int), stream);
  convert_w1_kernel<<<(N_FEAT * KPAD + 255) / 256, 256, 0, stream>>>(W1, W1T);
  csr_hist_kernel<<<eblocks, 256, 0, stream>>>(dst, bt, E, bw);
  csr_bucket_scan_kernel<<<1, 256, 0, stream>>>(bt, bucket_base, bucket_cursor);
  csr_stage_kernel<<<eblocks, 256, 0, stream>>>(src, dst, bucket_cursor, staging, E, bw);
  csr_final_kernel<<<NB, 256, 0, stream>>>(staging, bucket_base, row_ptr, sorted_src, dinv, N, bw, E);
  gemm1_mfma_kernel<<<(N + 63) / 64, 256, 0, stream>>>(features, W1T, dinv, G1, N);
  agg1_kernel<<<((size_t)N * 64 + 255) / 256, 256, 0, stream>>>(G1, row_ptr, sorted_src, dinv, b1, x1, N);
  gemm2_kernel<<<((size_t)N * 64 + 255) / 256, 256, 0, stream>>>(x1, W2, dinv, G2, N);
  agg2_kernel<<<((size_t)N * 64 + 255) / 256, 256, 0, stream>>>(G2, row_ptr, sorted_src, dinv, b2, out, N);
}

// Round 8
// 266.639 us; speedup vs baseline: 1.2132x; 1.2132x over previous
//
#include <hip/hip_runtime.h>
#include <hip/hip_bf16.h>

#define K_IN   1044
#define N_FEAT 128
#define KPAD   1056   // 33 * 32
#define LDA    40     // LDS row pitch in bf16 elems (32 + 8 pad = 80 B)
#define NSTEP  (KPAD / 32)   // 33
#define BM     96

#define NB     512    // coarse buckets for counting sort
#define BWMAX  256    // max nodes per bucket (runtime bw = ceil(N/NB) = 137)
#define EPB    8192   // edges per block in hist/stage

typedef __attribute__((ext_vector_type(8))) short short8;
typedef __attribute__((ext_vector_type(4))) float f32x4;

__device__ __forceinline__ ushort f2bf(float f) {
  unsigned x = __float_as_uint(f);
  x += 0x7fffu + ((x >> 16) & 1u);   // round-to-nearest-even
  return (ushort)(x >> 16);
}
// packed pair conversion: compiler lowers to v_cvt_pk_bf16_f32
__device__ __forceinline__ uint pkbf(float lo, float hi) {
  __hip_bfloat162 h = __float22bfloat162_rn(make_float2(lo, hi));
  return *reinterpret_cast<uint*>(&h);
}
__device__ __forceinline__ float bflo(uint v) { return __uint_as_float(v << 16); }
__device__ __forceinline__ float bfhi(uint v) { return __uint_as_float(v & 0xFFFF0000u); }

// ================= CSR build: bucketed counting sort =================

__global__ __launch_bounds__(256) void csr_hist_kernel(const int* __restrict__ dst,
                                                       int* __restrict__ bt, int E, int bw) {
  __shared__ int h[NB];
  const int t = threadIdx.x;
  for (int i = t; i < NB; i += 256) h[i] = 0;
  __syncthreads();
  const int e0 = blockIdx.x * EPB;
  const int e1 = min(e0 + EPB, E);
  for (int e = e0 + t; e < e1; e += 256) atomicAdd(&h[dst[e] / bw], 1);
  __syncthreads();
  for (int i = t; i < NB; i += 256)
    if (h[i]) atomicAdd(&bt[i], h[i]);
}

__global__ __launch_bounds__(256) void csr_bucket_scan_kernel(const int* __restrict__ bt,
                                                              int* __restrict__ bucket_base,
                                                              int* __restrict__ bucket_cursor) {
  __shared__ int sc[256];
  const int t = threadIdx.x;
  int v0 = bt[2 * t], v1 = bt[2 * t + 1];
  int s = v0 + v1;
  sc[t] = s;
  __syncthreads();
  for (int off = 1; off < 256; off <<= 1) {
    int x = (t >= off) ? sc[t - off] : 0;
    __syncthreads();
    sc[t] += x;
    __syncthreads();
  }
  int excl = sc[t] - s;
  bucket_base[2 * t]     = excl;
  bucket_base[2 * t + 1] = excl + v0;
  bucket_cursor[2 * t]     = excl;
  bucket_cursor[2 * t + 1] = excl + v0;
  if (t == 255) bucket_base[NB] = sc[255];
}

__global__ __launch_bounds__(256) void csr_stage_kernel(const int* __restrict__ src,
                                                        const int* __restrict__ dst,
                                                        int* __restrict__ bucket_cursor,
                                                        uint2* __restrict__ staging, int E, int bw) {
  __shared__ int h[NB];
  __shared__ int cur[NB];
  const int t = threadIdx.x;
  for (int i = t; i < NB; i += 256) h[i] = 0;
  __syncthreads();
  const int e0 = blockIdx.x * EPB;
  const int e1 = min(e0 + EPB, E);
  for (int e = e0 + t; e < e1; e += 256) atomicAdd(&h[dst[e] / bw], 1);
  __syncthreads();
  for (int i = t; i < NB; i += 256)
    cur[i] = h[i] ? atomicAdd(&bucket_cursor[i], h[i]) : 0;
  __syncthreads();
  for (int e = e0 + t; e < e1; e += 256) {
    int d = dst[e];
    int p = atomicAdd(&cur[d / bw], 1);
    staging[p] = make_uint2((uint)src[e], (uint)d);
  }
}

// one block per bucket: node histogram + scan + scatter -> row_ptr, sorted_src, dinv
__global__ __launch_bounds__(256) void csr_final_kernel(const uint2* __restrict__ staging,
                                                        const int* __restrict__ bucket_base,
                                                        int* __restrict__ row_ptr,
                                                        int* __restrict__ sorted_src,
                                                        float* __restrict__ dinv,
                                                        int N, int bw, int E) {
  __shared__ int hist[BWMAX];
  __shared__ int sc[256];
  const int b = blockIdx.x;
  const int t = threadIdx.x;
  if (b == 0 && t == 0) row_ptr[N] = E;
  const int node0 = b * bw;
  const int nn = min(bw, N - node0);
  if (nn <= 0) return;
  const int base = bucket_base[b];
  const int cnt  = bucket_base[b + 1] - base;

  for (int i = t; i < BWMAX; i += 256) hist[i] = 0;
  __syncthreads();
  for (int i = t; i < cnt; i += 256) {
    uint2 p = staging[base + i];
    atomicAdd(&hist[(int)p.y - node0], 1);
  }
  __syncthreads();
  int v = (t < nn) ? hist[t] : 0;
  if (t < nn) dinv[node0 + t] = rsqrtf((float)(v + 1));   // +1 self-loop
  sc[t] = v;
  __syncthreads();
  for (int off = 1; off < 256; off <<= 1) {
    int x = (t >= off) ? sc[t - off] : 0;
    __syncthreads();
    sc[t] += x;
    __syncthreads();
  }
  int excl = sc[t] - v;
  if (t < nn) row_ptr[node0 + t] = base + excl;
  if (t < nn) hist[t] = excl;   // reuse as cursors
  __syncthreads();
  for (int i = t; i < cnt; i += 256) {
    uint2 p = staging[base + i];
    int c = atomicAdd(&hist[(int)p.y - node0], 1);
    sorted_src[base + c] = (int)p.x;
  }
}

// ---------------- W1 -> bf16 transposed [128][KPAD] ----------------

__global__ void convert_w1_kernel(const float* __restrict__ W1, ushort* __restrict__ W1T) {
  int idx = blockIdx.x * blockDim.x + threadIdx.x;
  if (idx >= N_FEAT * KPAD) return;
  int c = idx / KPAD, k = idx - c * KPAD;
  W1T[idx] = (k < K_IN) ? f2bf(W1[(size_t)k * N_FEAT + c]) : (ushort)0;
}

// ---------------- layer 1 GEMM (MFMA bf16): g1 = dinv * (X @ W1), stored bf16 ----------------
// BM=96, BN=128, BK=32; 256 threads = 4 waves (2x2), wave tile 48x64 = 3x4 frags.
// R6-style simple double-buffer: prefetch next step's globals into registers
// before MFMA, convert+write the other LDS buffer after MFMA, one __syncthreads.

__global__ __launch_bounds__(256) void gemm1_mfma_kernel(const float* __restrict__ X,
                                                         const ushort* __restrict__ W1T,
                                                         const float* __restrict__ dinv,
                                                         ushort* __restrict__ G1, int M) {
  __shared__ ushort Asb[2][BM * LDA];    // 2 x 7.7 KB
  __shared__ ushort Bsb[2][128 * LDA];   // 2 x 10.2 KB

  const int t = threadIdx.x;
  const int row0 = blockIdx.x * BM;

  // A staging: 3 float4-chunks per thread; chunk c = t + i*256:
  // row = c>>3 (= r, r+32, r+64), k-offset (c&7)*4 (same for all 3)
  const int ar0 = t >> 3;           // 0..31
  const int ak4 = (t & 7) * 4;      // 0,4,...,28 (floats)
  // B staging: br = t>>1 (0..127), bk = (t&1)*16
  const int br = t >> 1;
  const int bk = (t & 1) * 16;

  const float*  aptr = X + (size_t)row0 * K_IN;
  const ushort* bptr = W1T + (size_t)br * KPAD;

  const int l = t & 63;
  const int wid = t >> 6;
  const int wm = wid >> 1, wn = wid & 1;
  const int lr = l & 15;
  const int lko = (l >> 4) * 8;

  f32x4 acc[3][4] = {};

  float4 pa[3];
  uint4 pb0, pb1;

  auto load_step = [&](int s) {
    const int kk = s * 32;
    const int gk = kk + ak4;
    #pragma unroll
    for (int i = 0; i < 3; i++) {
      const int row = ar0 + i * 32;
      const bool rv = (row0 + row) < M;
      if (rv && gk + 4 <= K_IN) {
        pa[i] = *(const float4*)(aptr + (size_t)row * K_IN + gk);
      } else {
        float tmp[4];
        #pragma unroll
        for (int j = 0; j < 4; j++)
          tmp[j] = (rv && gk + j < K_IN) ? aptr[(size_t)row * K_IN + gk + j] : 0.f;
        pa[i] = make_float4(tmp[0], tmp[1], tmp[2], tmp[3]);
      }
    }
    const uint4* q = (const uint4*)(bptr + kk + bk);
    pb0 = q[0]; pb1 = q[1];
  };
  auto store_step = [&](int buf) {
    #pragma unroll
    for (int i = 0; i < 3; i++) {
      uint w0 = pkbf(pa[i].x, pa[i].y), w1 = pkbf(pa[i].z, pa[i].w);
      *(uint2*)&Asb[buf][(ar0 + i * 32) * LDA + ak4] = make_uint2(w0, w1);
    }
    *(uint4*)&Bsb[buf][br * LDA + bk]     = pb0;
    *(uint4*)&Bsb[buf][br * LDA + bk + 8] = pb1;
  };

  load_step(0);
  store_step(0);
  __syncthreads();

  #pragma unroll 1
  for (int s = 0; s < NSTEP; s++) {
    const int cur = s & 1;
    if (s + 1 < NSTEP) load_step(s + 1);   // issue next-step globals early

    short8 af[3], bfr[4];
    #pragma unroll
    for (int m = 0; m < 3; m++)
      af[m] = *(const short8*)&Asb[cur][(wm * 48 + m * 16 + lr) * LDA + lko];
    #pragma unroll
    for (int n = 0; n < 4; n++)
      bfr[n] = *(const short8*)&Bsb[cur][(wn * 64 + n * 16 + lr) * LDA + lko];

    #pragma unroll
    for (int m = 0; m < 3; m++)
      #pragma unroll
      for (int n = 0; n < 4; n++)
        acc[m][n] = __builtin_amdgcn_mfma_f32_16x16x32_bf16(af[m], bfr[n], acc[m][n], 0, 0, 0);

    if (s + 1 < NSTEP) store_step(cur ^ 1);  // convert + write other buffer
    __syncthreads();
  }

  const int rbase = row0 + wm * 48 + (l >> 4) * 4;
  const int cbase = wn * 64 + lr;
  #pragma unroll
  for (int m = 0; m < 3; m++) {
    #pragma unroll
    for (int r = 0; r < 4; r++) {
      int row = rbase + m * 16 + r;
      if (row < M) {
        float dv = dinv[row];
        #pragma unroll
        for (int n = 0; n < 4; n++)
          G1[(size_t)row * N_FEAT + cbase + n * 16] = f2bf(dv * acc[m][n][r]);
      }
    }
  }
}

// ---------------- fused layer-1 aggregation + layer-2 GEMM ----------------
// per wave (node w): x1 channels 2co,2co+1 in registers -> dot with W2 -> G2 row.
// x1 is never materialized.

__global__ __launch_bounds__(256) void agg1mm_kernel(const ushort* __restrict__ G1,
                                                     const int* __restrict__ row_ptr,
                                                     const int* __restrict__ sorted_src,
                                                     const float* __restrict__ dinv,
                                                     const float* __restrict__ b1,
                                                     const float* __restrict__ W2,  // [128][3]
                                                     float* __restrict__ G2, int N) {
  const int w = (blockIdx.x * blockDim.x + threadIdx.x) >> 6;   // node
  const int lane = threadIdx.x & 63;
  if (w >= N) return;
  const int beg = row_ptr[w], end = row_ptr[w + 1];
  const uint* g1u = (const uint*)G1;
  const int co = lane;

  uint vs = g1u[((size_t)w << 6) + co];
  float a0 = bflo(vs), a1 = bfhi(vs);

  int e = beg;
  for (; e + 8 <= end; e += 8) {
    int s[8];
    #pragma unroll
    for (int i = 0; i < 8; i++) s[i] = sorted_src[e + i];
    #pragma unroll
    for (int i = 0; i < 8; i++) {
      uint v = g1u[((size_t)s[i] << 6) + co];
      a0 += bflo(v); a1 += bfhi(v);
    }
  }
  for (; e < end; e++) {
    uint v = g1u[((size_t)sorted_src[e] << 6) + co];
    a0 += bflo(v); a1 += bfhi(v);
  }

  const float di = dinv[w];
  float r0 = fmaxf(fmaf(di, a0, b1[2 * co + 0]), 0.f);   // x1[w][2co]
  float r1 = fmaxf(fmaf(di, a1, b1[2 * co + 1]), 0.f);   // x1[w][2co+1]

  // dot with W2 rows 2co, 2co+1
  const float* wrow = W2 + 6 * co;
  float s0 = r0 * wrow[0] + r1 * wrow[3];
  float s1 = r0 * wrow[1] + r1 * wrow[4];
  float s2 = r0 * wrow[2] + r1 * wrow[5];
  #pragma unroll
  for (int off = 32; off > 0; off >>= 1) {
    s0 += __shfl_down(s0, off);
    s1 += __shfl_down(s1, off);
    s2 += __shfl_down(s2, off);
  }
  if (lane == 0) {
    G2[w * 3 + 0] = di * s0;
    G2[w * 3 + 1] = di * s1;
    G2[w * 3 + 2] = di * s2;
  }
}

// ---------------- layer 2 aggregation ----------------

__global__ __launch_bounds__(256) void agg2_kernel(const float* __restrict__ G2,
                                                   const int* __restrict__ row_ptr,
                                                   const int* __restrict__ sorted_src,
                                                   const float* __restrict__ dinv,
                                                   const float* __restrict__ b2,
                                                   float* __restrict__ out, int N) {
  int t = blockIdx.x * blockDim.x + threadIdx.x;
  int node = t >> 6, lane = t & 63;
  if (node >= N) return;
  int beg = row_ptr[node], end = row_ptr[node + 1];
  float a0 = 0.f, a1 = 0.f, a2 = 0.f;
  for (int e = beg + lane; e < end; e += 64) {
    int s = sorted_src[e];
    a0 += G2[s * 3 + 0];
    a1 += G2[s * 3 + 1];
    a2 += G2[s * 3 + 2];
  }
  #pragma unroll
  for (int off = 32; off > 0; off >>= 1) {
    a0 += __shfl_down(a0, off);
    a1 += __shfl_down(a1, off);
    a2 += __shfl_down(a2, off);
  }
  if (lane == 0) {
    float di = dinv[node];
    out[node * 3 + 0] = di * (a0 + G2[node * 3 + 0]) + b2[0];
    out[node * 3 + 1] = di * (a1 + G2[node * 3 + 1]) + b2[1];
    out[node * 3 + 2] = di * (a2 + G2[node * 3 + 2]) + b2[2];
  }
}

// ---------------- launch ----------------

extern "C" void kernel_launch(void* const* d_in, const int* in_sizes, int n_in,
                              void* d_out, int out_size, void* d_ws, size_t ws_size,
                              hipStream_t stream) {
  const float* features = (const float*)d_in[0];
  const int*   edges    = (const int*)d_in[1];
  const float* W1 = (const float*)d_in[4];
  const float* b1 = (const float*)d_in[5];
  const float* W2 = (const float*)d_in[6];
  const float* b2 = (const float*)d_in[7];
  float* out = (float*)d_out;

  const int N = in_sizes[0] / K_IN;   // 70000
  const int E = in_sizes[1] / 2;      // 2,000,000
  const int* src = edges;
  const int* dst = edges + E;
  const int bw = (N + NB - 1) / NB;   // 137

  char* ws = (char*)d_ws;
  size_t off = 0;
  auto alloc = [&](size_t bytes) {
    void* p = ws + off;
    off += (bytes + 255) & ~(size_t)255;
    return p;
  };
  int*    bt            = (int*)   alloc((size_t)NB * sizeof(int));
  int*    bucket_base   = (int*)   alloc((size_t)(NB + 1) * sizeof(int));
  int*    bucket_cursor = (int*)   alloc((size_t)NB * sizeof(int));
  int*    row_ptr       = (int*)   alloc((size_t)(N + 1) * sizeof(int));
  float*  dinv          = (float*) alloc((size_t)N * sizeof(float));
  uint2*  staging       = (uint2*) alloc((size_t)E * sizeof(uint2));
  int*    sorted_src    = (int*)   alloc((size_t)E * sizeof(int));
  ushort* G1            = (ushort*)alloc((size_t)N * N_FEAT * sizeof(ushort));
  float*  G2            = (float*) alloc((size_t)N * 3 * sizeof(float));
  ushort* W1T           = (ushort*)alloc((size_t)N_FEAT * KPAD * sizeof(ushort));
  (void)ws_size;

  const int eblocks = (E + EPB - 1) / EPB;

  hipMemsetAsync(bt, 0, (size_t)NB * sizeof(int), stream);
  convert_w1_kernel<<<(N_FEAT * KPAD + 255) / 256, 256, 0, stream>>>(W1, W1T);
  csr_hist_kernel<<<eblocks, 256, 0, stream>>>(dst, bt, E, bw);
  csr_bucket_scan_kernel<<<1, 256, 0, stream>>>(bt, bucket_base, bucket_cursor);
  csr_stage_kernel<<<eblocks, 256, 0, stream>>>(src, dst, bucket_cursor, staging, E, bw);
  csr_final_kernel<<<NB, 256, 0, stream>>>(staging, bucket_base, row_ptr, sorted_src, dinv, N, bw, E);
  gemm1_mfma_kernel<<<(N + BM - 1) / BM, 256, 0, stream>>>(features, W1T, dinv, G1, N);
  agg1mm_kernel<<<((size_t)N * 64 + 255) / 256, 256, 0, stream>>>(G1, row_ptr, sorted_src, dinv, b1, W2, G2, N);
  agg2_kernel<<<((size_t)N * 64 + 255) / 256, 256, 0, stream>>>(G2, row_ptr, sorted_src, dinv, b2, out, N);
}

// Round 9
// 259.777 us; speedup vs baseline: 1.2452x; 1.0264x over previous
//
#include <hip/hip_runtime.h>
#include <hip/hip_bf16.h>

#define K_IN   1044
#define N_FEAT 128
#define KPAD   1056   // 33 * 32
#define NSTEP  (KPAD / 32)   // 33
#define BM     96

#define NB     512    // coarse buckets for counting sort
#define BWMAX  256    // max nodes per bucket (runtime bw = ceil(N/NB) = 137)
#define EPB    8192   // edges per block in hist/stage

typedef __attribute__((ext_vector_type(8))) short short8;
typedef __attribute__((ext_vector_type(4))) float f32x4;

__device__ __forceinline__ ushort f2bf(float f) {
  unsigned x = __float_as_uint(f);
  x += 0x7fffu + ((x >> 16) & 1u);   // round-to-nearest-even
  return (ushort)(x >> 16);
}
// packed pair conversion: compiler lowers to v_cvt_pk_bf16_f32
__device__ __forceinline__ uint pkbf(float lo, float hi) {
  __hip_bfloat162 h = __float22bfloat162_rn(make_float2(lo, hi));
  return *reinterpret_cast<uint*>(&h);
}
__device__ __forceinline__ float bflo(uint v) { return __uint_as_float(v << 16); }
__device__ __forceinline__ float bfhi(uint v) { return __uint_as_float(v & 0xFFFF0000u); }

// async global->LDS, 16B per lane; dest = wave-uniform base + lane*16 (HW)
__device__ __forceinline__ void gld16(const void* g, void* l) {
  __builtin_amdgcn_global_load_lds(
      (const __attribute__((address_space(1))) unsigned int*)g,
      (__attribute__((address_space(3))) unsigned int*)l, 16, 0, 0);
}

// ================= CSR build: bucketed counting sort =================

__global__ __launch_bounds__(256) void csr_hist_kernel(const int* __restrict__ dst,
                                                       int* __restrict__ bt, int E, int bw) {
  __shared__ int h[NB];
  const int t = threadIdx.x;
  for (int i = t; i < NB; i += 256) h[i] = 0;
  __syncthreads();
  const int e0 = blockIdx.x * EPB;
  const int e1 = min(e0 + EPB, E);
  for (int e = e0 + t; e < e1; e += 256) atomicAdd(&h[dst[e] / bw], 1);
  __syncthreads();
  for (int i = t; i < NB; i += 256)
    if (h[i]) atomicAdd(&bt[i], h[i]);
}

__global__ __launch_bounds__(256) void csr_bucket_scan_kernel(const int* __restrict__ bt,
                                                              int* __restrict__ bucket_base,
                                                              int* __restrict__ bucket_cursor) {
  __shared__ int sc[256];
  const int t = threadIdx.x;
  int v0 = bt[2 * t], v1 = bt[2 * t + 1];
  int s = v0 + v1;
  sc[t] = s;
  __syncthreads();
  for (int off = 1; off < 256; off <<= 1) {
    int x = (t >= off) ? sc[t - off] : 0;
    __syncthreads();
    sc[t] += x;
    __syncthreads();
  }
  int excl = sc[t] - s;
  bucket_base[2 * t]     = excl;
  bucket_base[2 * t + 1] = excl + v0;
  bucket_cursor[2 * t]     = excl;
  bucket_cursor[2 * t + 1] = excl + v0;
  if (t == 255) bucket_base[NB] = sc[255];
}

// staging entry: (src << 8) | (dst - bucket*bw), bw=137 < 256
__global__ __launch_bounds__(256) void csr_stage_kernel(const int* __restrict__ src,
                                                        const int* __restrict__ dst,
                                                        int* __restrict__ bucket_cursor,
                                                        uint* __restrict__ staging, int E, int bw) {
  __shared__ int h[NB];
  __shared__ int cur[NB];
  const int t = threadIdx.x;
  for (int i = t; i < NB; i += 256) h[i] = 0;
  __syncthreads();
  const int e0 = blockIdx.x * EPB;
  const int e1 = min(e0 + EPB, E);
  for (int e = e0 + t; e < e1; e += 256) atomicAdd(&h[dst[e] / bw], 1);
  __syncthreads();
  for (int i = t; i < NB; i += 256)
    cur[i] = h[i] ? atomicAdd(&bucket_cursor[i], h[i]) : 0;
  __syncthreads();
  for (int e = e0 + t; e < e1; e += 256) {
    int d = dst[e];
    int b = d / bw;
    int p = atomicAdd(&cur[b], 1);
    staging[p] = ((uint)src[e] << 8) | (uint)(d - b * bw);
  }
}

// one block per bucket: node histogram + scan + scatter -> row_ptr, sorted_src, dinv
__global__ __launch_bounds__(256) void csr_final_kernel(const uint* __restrict__ staging,
                                                        const int* __restrict__ bucket_base,
                                                        int* __restrict__ row_ptr,
                                                        int* __restrict__ sorted_src,
                                                        float* __restrict__ dinv,
                                                        int N, int bw, int E) {
  __shared__ int hist[BWMAX];
  __shared__ int sc[256];
  const int b = blockIdx.x;
  const int t = threadIdx.x;
  if (b == 0 && t == 0) row_ptr[N] = E;
  const int node0 = b * bw;
  const int nn = min(bw, N - node0);
  if (nn <= 0) return;
  const int base = bucket_base[b];
  const int cnt  = bucket_base[b + 1] - base;

  for (int i = t; i < BWMAX; i += 256) hist[i] = 0;
  __syncthreads();
  for (int i = t; i < cnt; i += 256)
    atomicAdd(&hist[staging[base + i] & 255u], 1);
  __syncthreads();
  int v = (t < nn) ? hist[t] : 0;
  if (t < nn) dinv[node0 + t] = rsqrtf((float)(v + 1));   // +1 self-loop
  sc[t] = v;
  __syncthreads();
  for (int off = 1; off < 256; off <<= 1) {
    int x = (t >= off) ? sc[t - off] : 0;
    __syncthreads();
    sc[t] += x;
    __syncthreads();
  }
  int excl = sc[t] - v;
  if (t < nn) row_ptr[node0 + t] = base + excl;
  if (t < nn) hist[t] = excl;   // reuse as cursors
  __syncthreads();
  for (int i = t; i < cnt; i += 256) {
    uint p = staging[base + i];
    int c = atomicAdd(&hist[p & 255u], 1);
    sorted_src[base + c] = (int)(p >> 8);
  }
}

// ---------------- W1 -> bf16 transposed [128][KPAD], chunk-swizzled ----------------
// Within each 32-k block, 8-bf16 chunk at linear pos jp holds logical chunk
// jl = jp ^ (col & 3), so global_load_lds's linear copy lands pre-swizzled in LDS.

__global__ void convert_w1_kernel(const float* __restrict__ W1, ushort* __restrict__ W1T) {
  int idx = blockIdx.x * blockDim.x + threadIdx.x;
  if (idx >= N_FEAT * KPAD) return;
  int col = idx / KPAD, k = idx - col * KPAD;
  int kk = k & ~31;
  int jp = (k >> 3) & 3;
  int e  = k & 7;
  int jl = jp ^ (col & 3);
  int ksrc = kk + 8 * jl + e;
  W1T[idx] = (ksrc < K_IN) ? f2bf(W1[(size_t)ksrc * N_FEAT + col]) : (ushort)0;
}

// ---------------- layer 1 GEMM (MFMA bf16): g1 = dinv * (X @ W1), stored bf16 ----------------
// BM=96, BN=128, BK=32; 4 waves (2x2), wave tile 48x64 = 3x4 frags of 16x16x32.
// m97 structure: both tiles staged via global_load_lds (width 16), double-buffered,
// one barrier per K-step. A stored fp32 (swizzle via per-lane source address,
// converted to bf16 at frag read); B bf16 (swizzle baked into W1T content).
// OOB rows/k are handled by clamping source addresses: clamped A slots hold
// finite garbage that multiplies W1T's zero padding (k>=1044) or lands in
// output rows >= M (discarded at the C-write).

__global__ __launch_bounds__(256) void gemm1_mfma_kernel(const float* __restrict__ X,
                                                         const ushort* __restrict__ W1T,
                                                         const float* __restrict__ dinv,
                                                         ushort* __restrict__ G1, int M) {
  __shared__ float  Af[2][BM * 32];      // 2 x 12 KB, packed 128 B rows
  __shared__ ushort Bsb[2][128 * 32];    // 2 x 8 KB, packed 64 B rows

  const int t = threadIdx.x;
  const int row0 = blockIdx.x * BM;
  const int w = t >> 6, l = t & 63;
  const int w24 = w * 24, w32 = w * 32;
  const int Mm1 = M - 1;

  const int wm = w >> 1, wn = w & 1;
  const int lr = l & 15, g = l >> 4;
  const int k7 = lr & 7, k3 = lr & 3;

  f32x4 acc[3][4] = {};

  auto stage = [&](int s, int buf) {
    const int kk = s * 32;
    // A: 3 instructions per wave, each covers 8 rows x 128 B
    #pragma unroll
    for (int i = 0; i < 3; i++) {
      int r  = w24 + i * 8 + (l >> 3);
      int jl = (l & 7) ^ (r & 7);                    // logical chunk this lane supplies
      int grow = min(row0 + r, Mm1);
      int gk   = min(kk + 4 * jl, K_IN - 4);
      gld16(X + (size_t)grow * K_IN + gk, (void*)&Af[buf][(w24 + i * 8) * 32]);
    }
    // B: 2 instructions per wave, each covers 16 cols x 64 B (content pre-swizzled)
    #pragma unroll
    for (int i = 0; i < 2; i++) {
      int r = w32 + i * 16 + (l >> 2);
      gld16(W1T + (size_t)r * KPAD + kk + 8 * (l & 3),
            (void*)&Bsb[buf][(w32 + i * 16) * 32]);
    }
  };

  stage(0, 0);
  __syncthreads();

  int cur = 0;
  #pragma unroll 1
  for (int s = 0; s < NSTEP; s++) {
    if (s + 1 < NSTEP) stage(s + 1, cur ^ 1);   // async into other buffer

    short8 af[3], bfr[4];
    #pragma unroll
    for (int m = 0; m < 3; m++) {
      const float* rp = &Af[cur][(wm * 48 + m * 16 + lr) * 32];
      float4 a0 = *(const float4*)&rp[((2 * g + 0) ^ k7) << 2];
      float4 a1 = *(const float4*)&rp[((2 * g + 1) ^ k7) << 2];
      uint4 uu = make_uint4(pkbf(a0.x, a0.y), pkbf(a0.z, a0.w),
                            pkbf(a1.x, a1.y), pkbf(a1.z, a1.w));
      af[m] = *(short8*)&uu;
    }
    #pragma unroll
    for (int n = 0; n < 4; n++)
      bfr[n] = *(const short8*)&Bsb[cur][(wn * 64 + n * 16 + lr) * 32 + ((g ^ k3) << 3)];

    #pragma unroll
    for (int m = 0; m < 3; m++)
      #pragma unroll
      for (int n = 0; n < 4; n++)
        acc[m][n] = __builtin_amdgcn_mfma_f32_16x16x32_bf16(af[m], bfr[n], acc[m][n], 0, 0, 0);

    __syncthreads();   // drains vmcnt (staged tile ready) + lgkm
    cur ^= 1;
  }

  const int rbase = row0 + wm * 48 + (l >> 4) * 4;
  const int cbase = wn * 64 + lr;
  #pragma unroll
  for (int m = 0; m < 3; m++) {
    #pragma unroll
    for (int r = 0; r < 4; r++) {
      int row = rbase + m * 16 + r;
      if (row < M) {
        float dv = dinv[row];
        #pragma unroll
        for (int n = 0; n < 4; n++)
          G1[(size_t)row * N_FEAT + cbase + n * 16] = f2bf(dv * acc[m][n][r]);
      }
    }
  }
}

// ---------------- fused layer-1 aggregation + layer-2 GEMM ----------------

__global__ __launch_bounds__(256) void agg1mm_kernel(const ushort* __restrict__ G1,
                                                     const int* __restrict__ row_ptr,
                                                     const int* __restrict__ sorted_src,
                                                     const float* __restrict__ dinv,
                                                     const float* __restrict__ b1,
                                                     const float* __restrict__ W2,  // [128][3]
                                                     float* __restrict__ G2, int N) {
  const int w = (blockIdx.x * blockDim.x + threadIdx.x) >> 6;   // node
  const int lane = threadIdx.x & 63;
  if (w >= N) return;
  const int beg = row_ptr[w], end = row_ptr[w + 1];
  const uint* g1u = (const uint*)G1;
  const int co = lane;

  uint vs = g1u[((size_t)w << 6) + co];
  float a0 = bflo(vs), a1 = bfhi(vs);

  int e = beg;
  for (; e + 8 <= end; e += 8) {
    int s[8];
    #pragma unroll
    for (int i = 0; i < 8; i++) s[i] = sorted_src[e + i];
    #pragma unroll
    for (int i = 0; i < 8; i++) {
      uint v = g1u[((size_t)s[i] << 6) + co];
      a0 += bflo(v); a1 += bfhi(v);
    }
  }
  for (; e < end; e++) {
    uint v = g1u[((size_t)sorted_src[e] << 6) + co];
    a0 += bflo(v); a1 += bfhi(v);
  }

  const float di = dinv[w];
  float r0 = fmaxf(fmaf(di, a0, b1[2 * co + 0]), 0.f);
  float r1 = fmaxf(fmaf(di, a1, b1[2 * co + 1]), 0.f);

  const float* wrow = W2 + 6 * co;
  float s0 = r0 * wrow[0] + r1 * wrow[3];
  float s1 = r0 * wrow[1] + r1 * wrow[4];
  float s2 = r0 * wrow[2] + r1 * wrow[5];
  #pragma unroll
  for (int off = 32; off > 0; off >>= 1) {
    s0 += __shfl_down(s0, off);
    s1 += __shfl_down(s1, off);
    s2 += __shfl_down(s2, off);
  }
  if (lane == 0) {
    G2[w * 3 + 0] = di * s0;
    G2[w * 3 + 1] = di * s1;
    G2[w * 3 + 2] = di * s2;
  }
}

// ---------------- layer 2 aggregation ----------------

__global__ __launch_bounds__(256) void agg2_kernel(const float* __restrict__ G2,
                                                   const int* __restrict__ row_ptr,
                                                   const int* __restrict__ sorted_src,
                                                   const float* __restrict__ dinv,
                                                   const float* __restrict__ b2,
                                                   float* __restrict__ out, int N) {
  int t = blockIdx.x * blockDim.x + threadIdx.x;
  int node = t >> 6, lane = t & 63;
  if (node >= N) return;
  int beg = row_ptr[node], end = row_ptr[node + 1];
  float a0 = 0.f, a1 = 0.f, a2 = 0.f;
  for (int e = beg + lane; e < end; e += 64) {
    int s = sorted_src[e];
    a0 += G2[s * 3 + 0];
    a1 += G2[s * 3 + 1];
    a2 += G2[s * 3 + 2];
  }
  #pragma unroll
  for (int off = 32; off > 0; off >>= 1) {
    a0 += __shfl_down(a0, off);
    a1 += __shfl_down(a1, off);
    a2 += __shfl_down(a2, off);
  }
  if (lane == 0) {
    float di = dinv[node];
    out[node * 3 + 0] = di * (a0 + G2[node * 3 + 0]) + b2[0];
    out[node * 3 + 1] = di * (a1 + G2[node * 3 + 1]) + b2[1];
    out[node * 3 + 2] = di * (a2 + G2[node * 3 + 2]) + b2[2];
  }
}

// ---------------- launch ----------------

extern "C" void kernel_launch(void* const* d_in, const int* in_sizes, int n_in,
                              void* d_out, int out_size, void* d_ws, size_t ws_size,
                              hipStream_t stream) {
  const float* features = (const float*)d_in[0];
  const int*   edges    = (const int*)d_in[1];
  const float* W1 = (const float*)d_in[4];
  const float* b1 = (const float*)d_in[5];
  const float* W2 = (const float*)d_in[6];
  const float* b2 = (const float*)d_in[7];
  float* out = (float*)d_out;

  const int N = in_sizes[0] / K_IN;   // 70000
  const int E = in_sizes[1] / 2;      // 2,000,000
  const int* src = edges;
  const int* dst = edges + E;
  const int bw = (N + NB - 1) / NB;   // 137

  char* ws = (char*)d_ws;
  size_t off = 0;
  auto alloc = [&](size_t bytes) {
    void* p = ws + off;
    off += (bytes + 255) & ~(size_t)255;
    return p;
  };
  int*    bt            = (int*)   alloc((size_t)NB * sizeof(int));
  int*    bucket_base   = (int*)   alloc((size_t)(NB + 1) * sizeof(int));
  int*    bucket_cursor = (int*)   alloc((size_t)NB * sizeof(int));
  int*    row_ptr       = (int*)   alloc((size_t)(N + 1) * sizeof(int));
  float*  dinv          = (float*) alloc((size_t)N * sizeof(float));
  uint*   staging       = (uint*)  alloc((size_t)E * sizeof(uint));
  int*    sorted_src    = (int*)   alloc((size_t)E * sizeof(int));
  ushort* G1            = (ushort*)alloc((size_t)N * N_FEAT * sizeof(ushort));
  float*  G2            = (float*) alloc((size_t)N * 3 * sizeof(float));
  ushort* W1T           = (ushort*)alloc((size_t)N_FEAT * KPAD * sizeof(ushort));
  (void)ws_size;

  const int eblocks = (E + EPB - 1) / EPB;

  hipMemsetAsync(bt, 0, (size_t)NB * sizeof(int), stream);
  convert_w1_kernel<<<(N_FEAT * KPAD + 255) / 256, 256, 0, stream>>>(W1, W1T);
  csr_hist_kernel<<<eblocks, 256, 0, stream>>>(dst, bt, E, bw);
  csr_bucket_scan_kernel<<<1, 256, 0, stream>>>(bt, bucket_base, bucket_cursor);
  csr_stage_kernel<<<eblocks, 256, 0, stream>>>(src, dst, bucket_cursor, staging, E, bw);
  csr_final_kernel<<<NB, 256, 0, stream>>>(staging, bucket_base, row_ptr, sorted_src, dinv, N, bw, E);
  gemm1_mfma_kernel<<<(N + BM - 1) / BM, 256, 0, stream>>>(features, W1T, dinv, G1, N);
  agg1mm_kernel<<<((size_t)N * 64 + 255) / 256, 256, 0, stream>>>(G1, row_ptr, sorted_src, dinv, b1, W2, G2, N);
  agg2_kernel<<<((size_t)N * 64 + 255) / 256, 256, 0, stream>>>(G2, row_ptr, sorted_src, dinv, b2, out, N);
}

// Round 10
// 255.223 us; speedup vs baseline: 1.2674x; 1.0178x over previous
//
#include <hip/hip_runtime.h>
#include <hip/hip_bf16.h>

#define K_IN   1044
#define N_FEAT 128
#define KPAD   1056   // 33 * 32
#define NSTEP  (KPAD / 32)   // 33
#define BM     96

#define NB     512    // coarse buckets for counting sort
#define BWMAX  256    // max nodes per bucket (runtime bw = ceil(N/NB) = 137)
#define EPB    8192   // edges per block in hist/stage

typedef __attribute__((ext_vector_type(8))) short short8;
typedef __attribute__((ext_vector_type(4))) float f32x4;

__device__ __forceinline__ ushort f2bf(float f) {
  unsigned x = __float_as_uint(f);
  x += 0x7fffu + ((x >> 16) & 1u);   // round-to-nearest-even
  return (ushort)(x >> 16);
}
// packed pair conversion: compiler lowers to v_cvt_pk_bf16_f32
__device__ __forceinline__ uint pkbf(float lo, float hi) {
  __hip_bfloat162 h = __float22bfloat162_rn(make_float2(lo, hi));
  return *reinterpret_cast<uint*>(&h);
}
__device__ __forceinline__ float bflo(uint v) { return __uint_as_float(v << 16); }
__device__ __forceinline__ float bfhi(uint v) { return __uint_as_float(v & 0xFFFF0000u); }

// async global->LDS, 16B per lane; dest = wave-uniform base + lane*16 (HW)
__device__ __forceinline__ void gld16(const void* g, void* l) {
  __builtin_amdgcn_global_load_lds(
      (const __attribute__((address_space(1))) unsigned int*)g,
      (__attribute__((address_space(3))) unsigned int*)l, 16, 0, 0);
}

// ================= CSR build: bucketed counting sort =================

__global__ __launch_bounds__(256) void csr_hist_kernel(const int* __restrict__ dst,
                                                       int* __restrict__ bt, int E, int bw) {
  __shared__ int h[NB];
  const int t = threadIdx.x;
  for (int i = t; i < NB; i += 256) h[i] = 0;
  __syncthreads();
  const int e0 = blockIdx.x * EPB;
  const int e1 = min(e0 + EPB, E);
  for (int e = e0 + t; e < e1; e += 256) atomicAdd(&h[dst[e] / bw], 1);
  __syncthreads();
  for (int i = t; i < NB; i += 256)
    if (h[i]) atomicAdd(&bt[i], h[i]);
}

__global__ __launch_bounds__(256) void csr_bucket_scan_kernel(const int* __restrict__ bt,
                                                              int* __restrict__ bucket_base,
                                                              int* __restrict__ bucket_cursor) {
  __shared__ int sc[256];
  const int t = threadIdx.x;
  int v0 = bt[2 * t], v1 = bt[2 * t + 1];
  int s = v0 + v1;
  sc[t] = s;
  __syncthreads();
  for (int off = 1; off < 256; off <<= 1) {
    int x = (t >= off) ? sc[t - off] : 0;
    __syncthreads();
    sc[t] += x;
    __syncthreads();
  }
  int excl = sc[t] - s;
  bucket_base[2 * t]     = excl;
  bucket_base[2 * t + 1] = excl + v0;
  bucket_cursor[2 * t]     = excl;
  bucket_cursor[2 * t + 1] = excl + v0;
  if (t == 255) bucket_base[NB] = sc[255];
}

// staging entry: (src << 8) | (dst - bucket*bw), bw=137 < 256
__global__ __launch_bounds__(256) void csr_stage_kernel(const int* __restrict__ src,
                                                        const int* __restrict__ dst,
                                                        int* __restrict__ bucket_cursor,
                                                        uint* __restrict__ staging, int E, int bw) {
  __shared__ int h[NB];
  __shared__ int cur[NB];
  const int t = threadIdx.x;
  for (int i = t; i < NB; i += 256) h[i] = 0;
  __syncthreads();
  const int e0 = blockIdx.x * EPB;
  const int e1 = min(e0 + EPB, E);
  for (int e = e0 + t; e < e1; e += 256) atomicAdd(&h[dst[e] / bw], 1);
  __syncthreads();
  for (int i = t; i < NB; i += 256)
    cur[i] = h[i] ? atomicAdd(&bucket_cursor[i], h[i]) : 0;
  __syncthreads();
  for (int e = e0 + t; e < e1; e += 256) {
    int d = dst[e];
    int b = d / bw;
    int p = atomicAdd(&cur[b], 1);
    staging[p] = ((uint)src[e] << 8) | (uint)(d - b * bw);
  }
}

// one block per bucket: node histogram + scan + scatter -> row_ptr, sorted_src, dinv
__global__ __launch_bounds__(256) void csr_final_kernel(const uint* __restrict__ staging,
                                                        const int* __restrict__ bucket_base,
                                                        int* __restrict__ row_ptr,
                                                        int* __restrict__ sorted_src,
                                                        float* __restrict__ dinv,
                                                        int N, int bw, int E) {
  __shared__ int hist[BWMAX];
  __shared__ int sc[256];
  const int b = blockIdx.x;
  const int t = threadIdx.x;
  if (b == 0 && t == 0) row_ptr[N] = E;
  const int node0 = b * bw;
  const int nn = min(bw, N - node0);
  if (nn <= 0) return;
  const int base = bucket_base[b];
  const int cnt  = bucket_base[b + 1] - base;

  for (int i = t; i < BWMAX; i += 256) hist[i] = 0;
  __syncthreads();
  for (int i = t; i < cnt; i += 256)
    atomicAdd(&hist[staging[base + i] & 255u], 1);
  __syncthreads();
  int v = (t < nn) ? hist[t] : 0;
  if (t < nn) dinv[node0 + t] = rsqrtf((float)(v + 1));   // +1 self-loop
  sc[t] = v;
  __syncthreads();
  for (int off = 1; off < 256; off <<= 1) {
    int x = (t >= off) ? sc[t - off] : 0;
    __syncthreads();
    sc[t] += x;
    __syncthreads();
  }
  int excl = sc[t] - v;
  if (t < nn) row_ptr[node0 + t] = base + excl;
  if (t < nn) hist[t] = excl;   // reuse as cursors
  __syncthreads();
  for (int i = t; i < cnt; i += 256) {
    uint p = staging[base + i];
    int c = atomicAdd(&hist[p & 255u], 1);
    sorted_src[base + c] = (int)(p >> 8);
  }
}

// ---------------- W1 -> bf16 transposed [128][KPAD], chunk-swizzled ----------------

__global__ void convert_w1_kernel(const float* __restrict__ W1, ushort* __restrict__ W1T) {
  int idx = blockIdx.x * blockDim.x + threadIdx.x;
  if (idx >= N_FEAT * KPAD) return;
  int col = idx / KPAD, k = idx - col * KPAD;
  int kk = k & ~31;
  int jp = (k >> 3) & 3;
  int e  = k & 7;
  int jl = jp ^ (col & 3);
  int ksrc = kk + 8 * jl + e;
  W1T[idx] = (ksrc < K_IN) ? f2bf(W1[(size_t)ksrc * N_FEAT + col]) : (ushort)0;
}

// ---------------- layer 1 GEMM (MFMA bf16): g1 = dinv * (X @ W1), stored bf16 ----------------
// BM=96, BN=128, BK=32; 4 waves (2x2), wave tile 48x64 = 3x4 frags of 16x16x32.
// T3/T4-lite: A triple-buffered (staged 2 steps ahead), B double-buffered (1 ahead),
// raw s_barrier with COUNTED s_waitcnt vmcnt(3): per-wave VMEM queue at each barrier
// is [B(s+1) x2 (older), A(s+2) x3 (newer)]; vmcnt(3) retires A(s+1)+B(s+1) while
// A(s+2) stays in flight across the barrier. Never drains to 0 in steady state.

__global__ __launch_bounds__(256) void gemm1_mfma_kernel(const float* __restrict__ X,
                                                         const ushort* __restrict__ W1T,
                                                         const float* __restrict__ dinv,
                                                         ushort* __restrict__ G1, int M) {
  __shared__ float  Af[3][BM * 32];      // 3 x 12 KB
  __shared__ ushort Bsb[2][128 * 32];    // 2 x 8 KB   (total 52 KB -> 3 blocks/CU)

  const int t = threadIdx.x;
  const int row0 = blockIdx.x * BM;
  const int w = t >> 6, l = t & 63;
  const int w24 = w * 24, w32 = w * 32;
  const int Mm1 = M - 1;

  const int wm = w >> 1, wn = w & 1;
  const int lr = l & 15, g = l >> 4;
  const int k7 = lr & 7, k3 = lr & 3;

  f32x4 acc[3][4] = {};

  auto stage_A = [&](int s, int buf) {
    const int kk = s * 32;
    #pragma unroll
    for (int i = 0; i < 3; i++) {
      int r  = w24 + i * 8 + (l >> 3);
      int jl = (l & 7) ^ (r & 7);                    // logical chunk this lane supplies
      int grow = min(row0 + r, Mm1);
      int gk   = min(kk + 4 * jl, K_IN - 4);
      gld16(X + (size_t)grow * K_IN + gk, (void*)&Af[buf][(w24 + i * 8) * 32]);
    }
  };
  auto stage_B = [&](int s, int buf) {
    const int kk = s * 32;
    #pragma unroll
    for (int i = 0; i < 2; i++) {
      int r = w32 + i * 16 + (l >> 2);
      gld16(W1T + (size_t)r * KPAD + kk + 8 * (l & 3),
            (void*)&Bsb[buf][(w32 + i * 16) * 32]);
    }
  };

  // prologue: queue = [A0 x3, B0 x2, A1 x3]; vmcnt(3) -> A0,B0 done, A1 in flight
  stage_A(0, 0);
  stage_B(0, 0);
  stage_A(1, 1);
  asm volatile("s_waitcnt vmcnt(3)" ::: "memory");
  __builtin_amdgcn_sched_barrier(0);
  __builtin_amdgcn_s_barrier();

  #pragma unroll 1
  for (int s = 0; s < NSTEP; s++) {
    const int ab = s % 3, bb = s & 1;
    if (s + 1 < NSTEP) stage_B(s + 1, (s + 1) & 1);   // issue B first (older in queue)
    if (s + 2 < NSTEP) stage_A(s + 2, (s + 2) % 3);

    short8 af[3], bfr[4];
    #pragma unroll
    for (int m = 0; m < 3; m++) {
      const float* rp = &Af[ab][(wm * 48 + m * 16 + lr) * 32];
      float4 a0 = *(const float4*)&rp[((2 * g + 0) ^ k7) << 2];
      float4 a1 = *(const float4*)&rp[((2 * g + 1) ^ k7) << 2];
      uint4 uu = make_uint4(pkbf(a0.x, a0.y), pkbf(a0.z, a0.w),
                            pkbf(a1.x, a1.y), pkbf(a1.z, a1.w));
      af[m] = *(short8*)&uu;
    }
    #pragma unroll
    for (int n = 0; n < 4; n++)
      bfr[n] = *(const short8*)&Bsb[bb][(wn * 64 + n * 16 + lr) * 32 + ((g ^ k3) << 3)];

    #pragma unroll
    for (int m = 0; m < 3; m++)
      #pragma unroll
      for (int n = 0; n < 4; n++)
        acc[m][n] = __builtin_amdgcn_mfma_f32_16x16x32_bf16(af[m], bfr[n], acc[m][n], 0, 0, 0);

    if (s + 2 < NSTEP) { asm volatile("s_waitcnt vmcnt(3)" ::: "memory"); }
    else               { asm volatile("s_waitcnt vmcnt(0)" ::: "memory"); }
    __builtin_amdgcn_sched_barrier(0);
    __builtin_amdgcn_s_barrier();
  }

  const int rbase = row0 + wm * 48 + (l >> 4) * 4;
  const int cbase = wn * 64 + lr;
  #pragma unroll
  for (int m = 0; m < 3; m++) {
    #pragma unroll
    for (int r = 0; r < 4; r++) {
      int row = rbase + m * 16 + r;
      if (row < M) {
        float dv = dinv[row];
        #pragma unroll
        for (int n = 0; n < 4; n++)
          G1[(size_t)row * N_FEAT + cbase + n * 16] = f2bf(dv * acc[m][n][r]);
      }
    }
  }
}

// ---------------- fused layer-1 aggregation + layer-2 GEMM ----------------
// G2 stored as float4 (padded) -> 1.12 MB, L2-resident per XCD for agg2's gathers.

__global__ __launch_bounds__(256) void agg1mm_kernel(const ushort* __restrict__ G1,
                                                     const int* __restrict__ row_ptr,
                                                     const int* __restrict__ sorted_src,
                                                     const float* __restrict__ dinv,
                                                     const float* __restrict__ b1,
                                                     const float* __restrict__ W2,  // [128][3]
                                                     float* __restrict__ G2, int N) {
  const int w = (blockIdx.x * blockDim.x + threadIdx.x) >> 6;   // node
  const int lane = threadIdx.x & 63;
  if (w >= N) return;
  const int beg = row_ptr[w], end = row_ptr[w + 1];
  const uint* g1u = (const uint*)G1;
  const int co = lane;

  uint vs = g1u[((size_t)w << 6) + co];
  float a0 = bflo(vs), a1 = bfhi(vs);

  int e = beg;
  for (; e + 8 <= end; e += 8) {
    int s[8];
    #pragma unroll
    for (int i = 0; i < 8; i++) s[i] = sorted_src[e + i];
    #pragma unroll
    for (int i = 0; i < 8; i++) {
      uint v = g1u[((size_t)s[i] << 6) + co];
      a0 += bflo(v); a1 += bfhi(v);
    }
  }
  for (; e < end; e++) {
    uint v = g1u[((size_t)sorted_src[e] << 6) + co];
    a0 += bflo(v); a1 += bfhi(v);
  }

  const float di = dinv[w];
  float r0 = fmaxf(fmaf(di, a0, b1[2 * co + 0]), 0.f);
  float r1 = fmaxf(fmaf(di, a1, b1[2 * co + 1]), 0.f);

  const float* wrow = W2 + 6 * co;
  float s0 = r0 * wrow[0] + r1 * wrow[3];
  float s1 = r0 * wrow[1] + r1 * wrow[4];
  float s2 = r0 * wrow[2] + r1 * wrow[5];
  #pragma unroll
  for (int off = 32; off > 0; off >>= 1) {
    s0 += __shfl_down(s0, off);
    s1 += __shfl_down(s1, off);
    s2 += __shfl_down(s2, off);
  }
  if (lane == 0) {
    *(float4*)&G2[(size_t)w * 4] = make_float4(di * s0, di * s1, di * s2, 0.f);
  }
}

// ---------------- layer 2 aggregation ----------------

__global__ __launch_bounds__(256) void agg2_kernel(const float* __restrict__ G2,  // [N][4]
                                                   const int* __restrict__ row_ptr,
                                                   const int* __restrict__ sorted_src,
                                                   const float* __restrict__ dinv,
                                                   const float* __restrict__ b2,
                                                   float* __restrict__ out, int N) {
  int t = blockIdx.x * blockDim.x + threadIdx.x;
  int node = t >> 6, lane = t & 63;
  if (node >= N) return;
  int beg = row_ptr[node], end = row_ptr[node + 1];
  float a0 = 0.f, a1 = 0.f, a2 = 0.f;
  for (int e = beg + lane; e < end; e += 64) {
    float4 v = *(const float4*)&G2[(size_t)sorted_src[e] * 4];
    a0 += v.x; a1 += v.y; a2 += v.z;
  }
  #pragma unroll
  for (int off = 32; off > 0; off >>= 1) {
    a0 += __shfl_down(a0, off);
    a1 += __shfl_down(a1, off);
    a2 += __shfl_down(a2, off);
  }
  if (lane == 0) {
    float di = dinv[node];
    float4 self = *(const float4*)&G2[(size_t)node * 4];
    out[node * 3 + 0] = di * (a0 + self.x) + b2[0];
    out[node * 3 + 1] = di * (a1 + self.y) + b2[1];
    out[node * 3 + 2] = di * (a2 + self.z) + b2[2];
  }
}

// ---------------- launch ----------------

extern "C" void kernel_launch(void* const* d_in, const int* in_sizes, int n_in,
                              void* d_out, int out_size, void* d_ws, size_t ws_size,
                              hipStream_t stream) {
  const float* features = (const float*)d_in[0];
  const int*   edges    = (const int*)d_in[1];
  const float* W1 = (const float*)d_in[4];
  const float* b1 = (const float*)d_in[5];
  const float* W2 = (const float*)d_in[6];
  const float* b2 = (const float*)d_in[7];
  float* out = (float*)d_out;

  const int N = in_sizes[0] / K_IN;   // 70000
  const int E = in_sizes[1] / 2;      // 2,000,000
  const int* src = edges;
  const int* dst = edges + E;
  const int bw = (N + NB - 1) / NB;   // 137

  char* ws = (char*)d_ws;
  size_t off = 0;
  auto alloc = [&](size_t bytes) {
    void* p = ws + off;
    off += (bytes + 255) & ~(size_t)255;
    return p;
  };
  int*    bt            = (int*)   alloc((size_t)NB * sizeof(int));
  int*    bucket_base   = (int*)   alloc((size_t)(NB + 1) * sizeof(int));
  int*    bucket_cursor = (int*)   alloc((size_t)NB * sizeof(int));
  int*    row_ptr       = (int*)   alloc((size_t)(N + 1) * sizeof(int));
  float*  dinv          = (float*) alloc((size_t)N * sizeof(float));
  uint*   staging       = (uint*)  alloc((size_t)E * sizeof(uint));
  int*    sorted_src    = (int*)   alloc((size_t)E * sizeof(int));
  ushort* G1            = (ushort*)alloc((size_t)N * N_FEAT * sizeof(ushort));
  float*  G2            = (float*) alloc((size_t)N * 4 * sizeof(float));
  ushort* W1T           = (ushort*)alloc((size_t)N_FEAT * KPAD * sizeof(ushort));
  (void)ws_size;

  const int eblocks = (E + EPB - 1) / EPB;

  hipMemsetAsync(bt, 0, (size_t)NB * sizeof(int), stream);
  convert_w1_kernel<<<(N_FEAT * KPAD + 255) / 256, 256, 0, stream>>>(W1, W1T);
  csr_hist_kernel<<<eblocks, 256, 0, stream>>>(dst, bt, E, bw);
  csr_bucket_scan_kernel<<<1, 256, 0, stream>>>(bt, bucket_base, bucket_cursor);
  csr_stage_kernel<<<eblocks, 256, 0, stream>>>(src, dst, bucket_cursor, staging, E, bw);
  csr_final_kernel<<<NB, 256, 0, stream>>>(staging, bucket_base, row_ptr, sorted_src, dinv, N, bw, E);
  gemm1_mfma_kernel<<<(N + BM - 1) / BM, 256, 0, stream>>>(features, W1T, dinv, G1, N);
  agg1mm_kernel<<<((size_t)N * 64 + 255) / 256, 256, 0, stream>>>(G1, row_ptr, sorted_src, dinv, b1, W2, G2, N);
  agg2_kernel<<<((size_t)N * 64 + 255) / 256, 256, 0, stream>>>(G2, row_ptr, sorted_src, dinv, b2, out, N);
}